// Round 2
// baseline (1142.577 us; speedup 1.0000x reference)
//
#include <hip/hip_runtime.h>
#include <cstdint>
#include <cstddef>

#define Bc 2
#define Sc 2048
#define Ec 1024
#define Hc 16
#define Dc 64
#define BSc 4096   // B*S
#define BHc 32     // B*H

typedef __attribute__((ext_vector_type(8))) short bf16x8;
typedef __attribute__((ext_vector_type(4))) float f32x4;

__device__ __forceinline__ uint16_t f2b(float x) {
  union { float f; uint32_t u; } v; v.f = x;
  return (uint16_t)((v.u + 0x7FFFu + ((v.u >> 16) & 1u)) >> 16);
}

// ---------------- prep: fp32 -> bf16 cast ----------------
__global__ void conv_bf16(const float* __restrict__ src, uint16_t* __restrict__ dst, int n) {
  int i = (blockIdx.x * blockDim.x + threadIdx.x) * 4;
  if (i < n) {
    float4 v = *(const float4*)(src + i);
    ushort4 o;
    o.x = f2b(v.x); o.y = f2b(v.y); o.z = f2b(v.z); o.w = f2b(v.w);
    *(ushort4*)(dst + i) = o;
  }
}

// ---------------- prep: W (K x N fp32) -> WT (N x K bf16) ----------------
__global__ void transpose_bf16(const float* __restrict__ src, uint16_t* __restrict__ dst) {
  __shared__ uint16_t tile[32][33];
  int x0 = blockIdx.x * 32, y0 = blockIdx.y * 32;
  int tx = threadIdx.x & 31, ty = threadIdx.x >> 5;  // 256 thr: ty 0..7
#pragma unroll
  for (int i = 0; i < 32; i += 8)
    tile[ty + i][tx] = f2b(src[(size_t)(y0 + ty + i) * 1024 + x0 + tx]);
  __syncthreads();
#pragma unroll
  for (int i = 0; i < 32; i += 8)
    dst[(size_t)(x0 + ty + i) * 1024 + y0 + tx] = tile[tx][ty + i];
}

// ---------------- prep: mask int32 -> packed bits ----------------
// pm[idx] = bits for mask[idx*64 .. idx*64+63], bit l set if masked
__global__ void pack_mask(const int* __restrict__ mask, unsigned long long* __restrict__ pm, int n64) {
  int idx = blockIdx.x * (blockDim.x >> 6) + (threadIdx.x >> 6);
  int lane = threadIdx.x & 63;
  if (idx < n64) {
    int v = mask[(size_t)idx * 64 + lane];
    unsigned long long b = __ballot(v != 0);
    if (lane == 0) pm[idx] = b;
  }
}

// ---------------- QKV projection GEMM ----------------
// A: M x K bf16 (M=4096,K=1024), BT: N x K bf16 (N=1024), bias fp32[N]
// mode 0: out[b][h][s][d]   mode 1: out[b][h][d][s]  (vT)
__global__ __launch_bounds__(256) void gemm_proj(
    const uint16_t* __restrict__ A, const uint16_t* __restrict__ BT,
    const float* __restrict__ bias, uint16_t* __restrict__ out, int mode) {
  const int K = 1024;
  __shared__ uint16_t As[128 * 40];
  __shared__ uint16_t Bs[128 * 40];
  int n0 = blockIdx.x * 128, m0 = blockIdx.y * 128;
  int t = threadIdx.x;
  int wave = t >> 6, lane = t & 63;
  int wm = (wave >> 1) * 64, wn = (wave & 1) * 64;
  int quad = lane >> 4, l16 = lane & 15;

  f32x4 acc[4][4];
#pragma unroll
  for (int i = 0; i < 4; i++)
#pragma unroll
    for (int j = 0; j < 4; j++) acc[i][j] = (f32x4)(0.0f);

  int srow = t >> 1, scol = (t & 1) * 16;  // thread loads 32B of a 64B tile-row

  for (int k0 = 0; k0 < K; k0 += 32) {
    const uint16_t* ag = A + (size_t)(m0 + srow) * K + k0 + scol;
    const uint16_t* bg = BT + (size_t)(n0 + srow) * K + k0 + scol;
    uint4 av0 = *(const uint4*)ag;
    uint4 av1 = *(const uint4*)(ag + 8);
    uint4 bv0 = *(const uint4*)bg;
    uint4 bv1 = *(const uint4*)(bg + 8);
    __syncthreads();
    *(uint4*)(As + srow * 40 + scol) = av0;
    *(uint4*)(As + srow * 40 + scol + 8) = av1;
    *(uint4*)(Bs + srow * 40 + scol) = bv0;
    *(uint4*)(Bs + srow * 40 + scol + 8) = bv1;
    __syncthreads();
    bf16x8 af[4], bfr[4];
#pragma unroll
    for (int i = 0; i < 4; i++)
      af[i] = *(const bf16x8*)(As + (wm + i * 16 + l16) * 40 + quad * 8);
#pragma unroll
    for (int j = 0; j < 4; j++)
      bfr[j] = *(const bf16x8*)(Bs + (wn + j * 16 + l16) * 40 + quad * 8);
#pragma unroll
    for (int i = 0; i < 4; i++)
#pragma unroll
      for (int j = 0; j < 4; j++)
        acc[i][j] = __builtin_amdgcn_mfma_f32_16x16x32_bf16(af[i], bfr[j], acc[i][j], 0, 0, 0);
  }
#pragma unroll
  for (int i = 0; i < 4; i++)
#pragma unroll
    for (int j = 0; j < 4; j++) {
      int col = n0 + wn + j * 16 + l16;
      float bval = bias[col];
      int h = col >> 6, d = col & 63;
#pragma unroll
      for (int r = 0; r < 4; r++) {
        int row = m0 + wm + i * 16 + quad * 4 + r;
        int b = row >> 11, s = row & 2047;
        uint16_t hv = f2b(acc[i][j][r] + bval);
        if (mode == 0)
          out[(size_t)((b * Hc + h) * Sc + s) * Dc + d] = hv;
        else
          out[(size_t)((b * Hc + h) * Dc + d) * Sc + s] = hv;
      }
    }
}

// ---------------- output projection GEMM + bias + residual ----------------
__global__ __launch_bounds__(256) void gemm_out(
    const uint16_t* __restrict__ A, const uint16_t* __restrict__ BT,
    const float* __restrict__ bias, const float* __restrict__ resid,
    float* __restrict__ x) {
  const int K = 1024;
  __shared__ uint16_t As[128 * 40];
  __shared__ uint16_t Bs[128 * 40];
  int n0 = blockIdx.x * 128, m0 = blockIdx.y * 128;
  int t = threadIdx.x;
  int wave = t >> 6, lane = t & 63;
  int wm = (wave >> 1) * 64, wn = (wave & 1) * 64;
  int quad = lane >> 4, l16 = lane & 15;

  f32x4 acc[4][4];
#pragma unroll
  for (int i = 0; i < 4; i++)
#pragma unroll
    for (int j = 0; j < 4; j++) acc[i][j] = (f32x4)(0.0f);

  int srow = t >> 1, scol = (t & 1) * 16;
  for (int k0 = 0; k0 < K; k0 += 32) {
    const uint16_t* ag = A + (size_t)(m0 + srow) * K + k0 + scol;
    const uint16_t* bg = BT + (size_t)(n0 + srow) * K + k0 + scol;
    uint4 av0 = *(const uint4*)ag;
    uint4 av1 = *(const uint4*)(ag + 8);
    uint4 bv0 = *(const uint4*)bg;
    uint4 bv1 = *(const uint4*)(bg + 8);
    __syncthreads();
    *(uint4*)(As + srow * 40 + scol) = av0;
    *(uint4*)(As + srow * 40 + scol + 8) = av1;
    *(uint4*)(Bs + srow * 40 + scol) = bv0;
    *(uint4*)(Bs + srow * 40 + scol + 8) = bv1;
    __syncthreads();
    bf16x8 af[4], bfr[4];
#pragma unroll
    for (int i = 0; i < 4; i++)
      af[i] = *(const bf16x8*)(As + (wm + i * 16 + l16) * 40 + quad * 8);
#pragma unroll
    for (int j = 0; j < 4; j++)
      bfr[j] = *(const bf16x8*)(Bs + (wn + j * 16 + l16) * 40 + quad * 8);
#pragma unroll
    for (int i = 0; i < 4; i++)
#pragma unroll
      for (int j = 0; j < 4; j++)
        acc[i][j] = __builtin_amdgcn_mfma_f32_16x16x32_bf16(af[i], bfr[j], acc[i][j], 0, 0, 0);
  }
#pragma unroll
  for (int i = 0; i < 4; i++)
#pragma unroll
    for (int j = 0; j < 4; j++) {
      int col = n0 + wn + j * 16 + l16;
      float bval = bias[col];
#pragma unroll
      for (int r = 0; r < 4; r++) {
        int row = m0 + wm + i * 16 + quad * 4 + r;
        x[(size_t)row * 1024 + col] = acc[i][j][r] + bval + resid[(size_t)row * 1024 + col];
      }
    }
}

// ---------------- fused attention: barrier-free, K/V direct global->reg ----------------
// Swapped-operand QK^T: sacc = mfma(K_frag, Q_frag); each lane owns q-row l16.
// Pass 1: rowsum only (no stores). shfl_xor(16)+shfl_xor(32) gives every lane
// the full row sum -> rv in-register (no LDS broadcast, no barrier).
// Pass 2: recompute scores, normalize, write attn once (float4), stage P bf16
// into WAVE-PRIVATE LDS for the PV A-fragment relayout, accumulate PV.
// Zero __syncthreads in the whole kernel: compiler pipelines with counted vmcnt.
__global__ __launch_bounds__(256) void fused_attn(
    const uint16_t* __restrict__ qh,              // [BH,S,64]
    const uint16_t* __restrict__ kh,              // [BH,S,64]
    const uint16_t* __restrict__ vT,              // [BH,64,S]
    const unsigned long long* __restrict__ pmask, // [B*S, S/64] bit set -> masked
    float* __restrict__ attn,                     // [BH,S,S] normalized out
    uint16_t* __restrict__ ctx) {                 // [B,S,H*64]
  __shared__ uint16_t Ps[4][16 * 72];             // per-wave P tile [qrow][key]

  int m0 = blockIdx.x * 64;
  int bh = blockIdx.y;
  int b = bh >> 4;
  int t = threadIdx.x;
  int wave = t >> 6, lane = t & 63;
  int quad = lane >> 4, l16 = lane & 15;

  int m = m0 + wave * 16 + l16;  // this lane's q-row
  const unsigned long long* pmr = pmask + (size_t)(b * Sc + m) * (Sc / 64);

  // loop-invariant Q fragments (B-operand)
  const uint16_t* qg = qh + (size_t)(bh * Sc + m) * Dc;
  bf16x8 qf0 = *(const bf16x8*)(qg + quad * 8);
  bf16x8 qf1 = *(const bf16x8*)(qg + 32 + quad * 8);

  const uint16_t* kbase = kh + (size_t)bh * Sc * Dc;
  const uint16_t* vbase = vT + (size_t)bh * Dc * Sc;

  // ---------------- pass 1: rowsums ----------------
  float rs = 0.0f;
  for (int k0 = 0; k0 < Sc; k0 += 64) {
    unsigned long long mk = pmr[k0 >> 6];
    f32x4 sacc[4];
#pragma unroll
    for (int j = 0; j < 4; j++) sacc[j] = (f32x4)(0.0f);
#pragma unroll
    for (int j = 0; j < 4; j++) {
      const uint16_t* kg = kbase + (size_t)(k0 + j * 16 + l16) * Dc + quad * 8;
      bf16x8 kf0 = *(const bf16x8*)kg;
      bf16x8 kf1 = *(const bf16x8*)(kg + 32);
      sacc[j] = __builtin_amdgcn_mfma_f32_16x16x32_bf16(kf0, qf0, sacc[j], 0, 0, 0);
      sacc[j] = __builtin_amdgcn_mfma_f32_16x16x32_bf16(kf1, qf1, sacc[j], 0, 0, 0);
    }
#pragma unroll
    for (int j = 0; j < 4; j++) {
      int base = j * 16 + quad * 4;
#pragma unroll
      for (int r = 0; r < 4; r++) {
        float e = __expf(sacc[j][r] * 0.125f);
        rs += ((mk >> (base + r)) & 1ull) ? 0.0f : e;
      }
    }
  }
  // sum the 4 quads holding the same q-row -> every lane gets the full sum
  rs += __shfl_xor(rs, 16);
  rs += __shfl_xor(rs, 32);
  float rv = 1.0f / rs;

  // ---------------- pass 2: normalize + write attn + PV ----------------
  f32x4 cacc[4];
#pragma unroll
  for (int j = 0; j < 4; j++) cacc[j] = (f32x4)(0.0f);
  uint16_t* Pw = Ps[wave];

  for (int k0 = 0; k0 < Sc; k0 += 64) {
    unsigned long long mk = pmr[k0 >> 6];
    f32x4 sacc[4];
#pragma unroll
    for (int j = 0; j < 4; j++) sacc[j] = (f32x4)(0.0f);
#pragma unroll
    for (int j = 0; j < 4; j++) {
      const uint16_t* kg = kbase + (size_t)(k0 + j * 16 + l16) * Dc + quad * 8;
      bf16x8 kf0 = *(const bf16x8*)kg;
      bf16x8 kf1 = *(const bf16x8*)(kg + 32);
      sacc[j] = __builtin_amdgcn_mfma_f32_16x16x32_bf16(kf0, qf0, sacc[j], 0, 0, 0);
      sacc[j] = __builtin_amdgcn_mfma_f32_16x16x32_bf16(kf1, qf1, sacc[j], 0, 0, 0);
    }
    float* arow = attn + (size_t)(bh * Sc + m) * Sc + k0;
#pragma unroll
    for (int j = 0; j < 4; j++) {
      int base = j * 16 + quad * 4;
      float p0 = ((mk >> (base + 0)) & 1ull) ? 0.0f : __expf(sacc[j][0] * 0.125f) * rv;
      float p1 = ((mk >> (base + 1)) & 1ull) ? 0.0f : __expf(sacc[j][1] * 0.125f) * rv;
      float p2 = ((mk >> (base + 2)) & 1ull) ? 0.0f : __expf(sacc[j][2] * 0.125f) * rv;
      float p3 = ((mk >> (base + 3)) & 1ull) ? 0.0f : __expf(sacc[j][3] * 0.125f) * rv;
      *(float4*)(arow + base) = make_float4(p0, p1, p2, p3);
      union { uint16_t u[4]; uint2 v; } pk;
      pk.u[0] = f2b(p0); pk.u[1] = f2b(p1); pk.u[2] = f2b(p2); pk.u[3] = f2b(p3);
      *(uint2*)(Pw + l16 * 72 + base) = pk.v;  // wave-private: no barrier needed
    }
    // PV: A = P[qrow][key] fragment via LDS relayout, B = V^T[d][key] from global
    bf16x8 pf0 = *(const bf16x8*)(Pw + l16 * 72 + quad * 8);
    bf16x8 pf1 = *(const bf16x8*)(Pw + l16 * 72 + 32 + quad * 8);
#pragma unroll
    for (int j = 0; j < 4; j++) {
      const uint16_t* vg = vbase + (size_t)(j * 16 + l16) * Sc + k0 + quad * 8;
      bf16x8 vf0 = *(const bf16x8*)vg;
      bf16x8 vf1 = *(const bf16x8*)(vg + 32);
      cacc[j] = __builtin_amdgcn_mfma_f32_16x16x32_bf16(pf0, vf0, cacc[j], 0, 0, 0);
      cacc[j] = __builtin_amdgcn_mfma_f32_16x16x32_bf16(pf1, vf1, cacc[j], 0, 0, 0);
    }
  }
  // epilogue: ctx write (C-layout: row = quad*4+r within wave's 16 rows, col=l16)
  int h = bh & 15;
#pragma unroll
  for (int j = 0; j < 4; j++) {
    int d = j * 16 + l16;
#pragma unroll
    for (int r = 0; r < 4; r++) {
      int s = m0 + wave * 16 + quad * 4 + r;
      ctx[(size_t)(b * Sc + s) * (Hc * Dc) + h * Dc + d] = f2b(cacc[j][r]);
    }
  }
}

// ---------------- LayerNorm ----------------
__global__ __launch_bounds__(256) void ln_kernel(
    const float* __restrict__ x, const float* __restrict__ gamma,
    const float* __restrict__ beta, float* __restrict__ y) {
  int row = blockIdx.x;
  int t = threadIdx.x;
  const float* xr = x + (size_t)row * 1024;
  float4 v = *(const float4*)(xr + t * 4);
  float s = v.x + v.y + v.z + v.w;
  float s2 = v.x * v.x + v.y * v.y + v.z * v.z + v.w * v.w;
#pragma unroll
  for (int o = 1; o < 64; o <<= 1) {
    s += __shfl_xor(s, o);
    s2 += __shfl_xor(s2, o);
  }
  __shared__ float ss[4], ss2[4];
  int wave = t >> 6, lane = t & 63;
  if (lane == 0) { ss[wave] = s; ss2[wave] = s2; }
  __syncthreads();
  s = ss[0] + ss[1] + ss[2] + ss[3];
  s2 = ss2[0] + ss2[1] + ss2[2] + ss2[3];
  float mu = s * (1.0f / 1024.0f);
  float var = s2 * (1.0f / 1024.0f) - mu * mu;
  float rstd = rsqrtf(var + 1e-5f);
  float4 g = *(const float4*)(gamma + t * 4);
  float4 be = *(const float4*)(beta + t * 4);
  float4 o;
  o.x = (v.x - mu) * rstd * g.x + be.x;
  o.y = (v.y - mu) * rstd * g.y + be.y;
  o.z = (v.z - mu) * rstd * g.z + be.z;
  o.w = (v.w - mu) * rstd * g.w + be.w;
  *(float4*)(y + (size_t)row * 1024 + t * 4) = o;
}

extern "C" void kernel_launch(void* const* d_in, const int* in_sizes, int n_in,
                              void* d_out, int out_size, void* d_ws, size_t ws_size,
                              hipStream_t stream) {
  const float* Q = (const float*)d_in[0];
  const float* K = (const float*)d_in[1];
  const float* V = (const float*)d_in[2];
  const int* mask = (const int*)d_in[3];
  const float* Wq = (const float*)d_in[4];
  const float* bq = (const float*)d_in[5];
  const float* Wk = (const float*)d_in[6];
  const float* bk = (const float*)d_in[7];
  const float* Wv = (const float*)d_in[8];
  const float* bv = (const float*)d_in[9];
  const float* Wo = (const float*)d_in[10];
  const float* bo = (const float*)d_in[11];
  const float* gamma = (const float*)d_in[12];
  const float* beta = (const float*)d_in[13];

  float* y = (float*)d_out;                           // [B,S,E]
  float* attn = (float*)d_out + (size_t)BSc * Ec;     // [B,H,S,S]

  char* ws = (char*)d_ws;
  size_t off = 0;
  auto alloc = [&](size_t bytes) -> void* {
    void* p = ws + off;
    off = (off + bytes + 255) & ~(size_t)255;
    return p;
  };
  uint16_t* Qb  = (uint16_t*)alloc((size_t)BSc * Ec * 2);
  uint16_t* Kb  = (uint16_t*)alloc((size_t)BSc * Ec * 2);
  uint16_t* Vb  = (uint16_t*)alloc((size_t)BSc * Ec * 2);
  uint16_t* WqT = (uint16_t*)alloc((size_t)Ec * Ec * 2);
  uint16_t* WkT = (uint16_t*)alloc((size_t)Ec * Ec * 2);
  uint16_t* WvT = (uint16_t*)alloc((size_t)Ec * Ec * 2);
  uint16_t* WoT = (uint16_t*)alloc((size_t)Ec * Ec * 2);
  uint16_t* qh  = (uint16_t*)alloc((size_t)BHc * Sc * Dc * 2);  // [BH,S,64]
  uint16_t* kh  = (uint16_t*)alloc((size_t)BHc * Sc * Dc * 2);  // [BH,S,64]
  uint16_t* vT  = (uint16_t*)alloc((size_t)BHc * Dc * Sc * 2);  // [BH,64,S]
  uint16_t* ctx = (uint16_t*)alloc((size_t)BSc * Ec * 2);       // [B,S,1024]
  float* xres   = (float*)alloc((size_t)BSc * Ec * 4);
  unsigned long long* pm = (unsigned long long*)alloc((size_t)Bc * Sc * (Sc / 64) * 8);

  const int n_qkv = BSc * Ec;  // 4,194,304
  const int n64 = Bc * Sc * (Sc / 64);  // 131072

  // 1) casts + mask pack
  conv_bf16<<<n_qkv / 1024, 256, 0, stream>>>(Q, Qb, n_qkv);
  conv_bf16<<<n_qkv / 1024, 256, 0, stream>>>(K, Kb, n_qkv);
  conv_bf16<<<n_qkv / 1024, 256, 0, stream>>>(V, Vb, n_qkv);
  pack_mask<<<n64 / 4, 256, 0, stream>>>(mask, pm, n64);
  // 2) weight transposes
  dim3 tg(32, 32);
  transpose_bf16<<<tg, 256, 0, stream>>>(Wq, WqT);
  transpose_bf16<<<tg, 256, 0, stream>>>(Wk, WkT);
  transpose_bf16<<<tg, 256, 0, stream>>>(Wv, WvT);
  transpose_bf16<<<tg, 256, 0, stream>>>(Wo, WoT);
  // 3) QKV projections
  dim3 pg(Ec / 128, BSc / 128);  // (8, 32)
  gemm_proj<<<pg, 256, 0, stream>>>(Qb, WqT, bq, qh, 0);
  gemm_proj<<<pg, 256, 0, stream>>>(Kb, WkT, bk, kh, 0);
  gemm_proj<<<pg, 256, 0, stream>>>(Vb, WvT, bv, vT, 1);
  // 4) fused attention (barrier-free)
  dim3 fg(Sc / 64, BHc);  // (32, 32)
  fused_attn<<<fg, 256, 0, stream>>>(qh, kh, vT, pm, attn, ctx);
  // 5) out projection + residual
  gemm_out<<<pg, 256, 0, stream>>>(ctx, WoT, bo, Q, xres);
  // 6) LayerNorm
  ln_kernel<<<BSc, 256, 0, stream>>>(xres, gamma, beta, y);
}

// Round 3
// 910.063 us; speedup vs baseline: 1.2555x; 1.2555x over previous
//
#include <hip/hip_runtime.h>
#include <cstdint>
#include <cstddef>

#define Bc 2
#define Sc 2048
#define Ec 1024
#define Hc 16
#define Dc 64
#define BSc 4096   // B*S
#define BHc 32     // B*H

typedef __attribute__((ext_vector_type(8))) short bf16x8;
typedef __attribute__((ext_vector_type(4))) float f32x4;

__device__ __forceinline__ uint16_t f2b(float x) {
  union { float f; uint32_t u; } v; v.f = x;
  return (uint16_t)((v.u + 0x7FFFu + ((v.u >> 16) & 1u)) >> 16);
}

// ---------------- prep: fp32 -> bf16 cast ----------------
__global__ void conv_bf16(const float* __restrict__ src, uint16_t* __restrict__ dst, int n) {
  int i = (blockIdx.x * blockDim.x + threadIdx.x) * 4;
  if (i < n) {
    float4 v = *(const float4*)(src + i);
    ushort4 o;
    o.x = f2b(v.x); o.y = f2b(v.y); o.z = f2b(v.z); o.w = f2b(v.w);
    *(ushort4*)(dst + i) = o;
  }
}

// ---------------- prep: W (K x N fp32) -> WT (N x K bf16) ----------------
__global__ void transpose_bf16(const float* __restrict__ src, uint16_t* __restrict__ dst) {
  __shared__ uint16_t tile[32][33];
  int x0 = blockIdx.x * 32, y0 = blockIdx.y * 32;
  int tx = threadIdx.x & 31, ty = threadIdx.x >> 5;  // 256 thr: ty 0..7
#pragma unroll
  for (int i = 0; i < 32; i += 8)
    tile[ty + i][tx] = f2b(src[(size_t)(y0 + ty + i) * 1024 + x0 + tx]);
  __syncthreads();
#pragma unroll
  for (int i = 0; i < 32; i += 8)
    dst[(size_t)(x0 + ty + i) * 1024 + y0 + tx] = tile[tx][ty + i];
}

// ---------------- prep: mask int32 -> packed bits ----------------
__global__ void pack_mask(const int* __restrict__ mask, unsigned long long* __restrict__ pm, int n64) {
  int idx = blockIdx.x * (blockDim.x >> 6) + (threadIdx.x >> 6);
  int lane = threadIdx.x & 63;
  if (idx < n64) {
    int v = mask[(size_t)idx * 64 + lane];
    unsigned long long b = __ballot(v != 0);
    if (lane == 0) pm[idx] = b;
  }
}

// ---------------- QKV projection GEMM ----------------
__global__ __launch_bounds__(256) void gemm_proj(
    const uint16_t* __restrict__ A, const uint16_t* __restrict__ BT,
    const float* __restrict__ bias, uint16_t* __restrict__ out, int mode) {
  const int K = 1024;
  __shared__ uint16_t As[128 * 40];
  __shared__ uint16_t Bs[128 * 40];
  int n0 = blockIdx.x * 128, m0 = blockIdx.y * 128;
  int t = threadIdx.x;
  int wave = t >> 6, lane = t & 63;
  int wm = (wave >> 1) * 64, wn = (wave & 1) * 64;
  int quad = lane >> 4, l16 = lane & 15;

  f32x4 acc[4][4];
#pragma unroll
  for (int i = 0; i < 4; i++)
#pragma unroll
    for (int j = 0; j < 4; j++) acc[i][j] = (f32x4)(0.0f);

  int srow = t >> 1, scol = (t & 1) * 16;

  for (int k0 = 0; k0 < K; k0 += 32) {
    const uint16_t* ag = A + (size_t)(m0 + srow) * K + k0 + scol;
    const uint16_t* bg = BT + (size_t)(n0 + srow) * K + k0 + scol;
    uint4 av0 = *(const uint4*)ag;
    uint4 av1 = *(const uint4*)(ag + 8);
    uint4 bv0 = *(const uint4*)bg;
    uint4 bv1 = *(const uint4*)(bg + 8);
    __syncthreads();
    *(uint4*)(As + srow * 40 + scol) = av0;
    *(uint4*)(As + srow * 40 + scol + 8) = av1;
    *(uint4*)(Bs + srow * 40 + scol) = bv0;
    *(uint4*)(Bs + srow * 40 + scol + 8) = bv1;
    __syncthreads();
    bf16x8 af[4], bfr[4];
#pragma unroll
    for (int i = 0; i < 4; i++)
      af[i] = *(const bf16x8*)(As + (wm + i * 16 + l16) * 40 + quad * 8);
#pragma unroll
    for (int j = 0; j < 4; j++)
      bfr[j] = *(const bf16x8*)(Bs + (wn + j * 16 + l16) * 40 + quad * 8);
#pragma unroll
    for (int i = 0; i < 4; i++)
#pragma unroll
      for (int j = 0; j < 4; j++)
        acc[i][j] = __builtin_amdgcn_mfma_f32_16x16x32_bf16(af[i], bfr[j], acc[i][j], 0, 0, 0);
  }
#pragma unroll
  for (int i = 0; i < 4; i++)
#pragma unroll
    for (int j = 0; j < 4; j++) {
      int col = n0 + wn + j * 16 + l16;
      float bval = bias[col];
      int h = col >> 6, d = col & 63;
#pragma unroll
      for (int r = 0; r < 4; r++) {
        int row = m0 + wm + i * 16 + quad * 4 + r;
        int b = row >> 11, s = row & 2047;
        uint16_t hv = f2b(acc[i][j][r] + bval);
        if (mode == 0)
          out[(size_t)((b * Hc + h) * Sc + s) * Dc + d] = hv;
        else
          out[(size_t)((b * Hc + h) * Dc + d) * Sc + s] = hv;
      }
    }
}

// ---------------- output projection GEMM + bias + residual ----------------
__global__ __launch_bounds__(256) void gemm_out(
    const uint16_t* __restrict__ A, const uint16_t* __restrict__ BT,
    const float* __restrict__ bias, const float* __restrict__ resid,
    float* __restrict__ x) {
  const int K = 1024;
  __shared__ uint16_t As[128 * 40];
  __shared__ uint16_t Bs[128 * 40];
  int n0 = blockIdx.x * 128, m0 = blockIdx.y * 128;
  int t = threadIdx.x;
  int wave = t >> 6, lane = t & 63;
  int wm = (wave >> 1) * 64, wn = (wave & 1) * 64;
  int quad = lane >> 4, l16 = lane & 15;

  f32x4 acc[4][4];
#pragma unroll
  for (int i = 0; i < 4; i++)
#pragma unroll
    for (int j = 0; j < 4; j++) acc[i][j] = (f32x4)(0.0f);

  int srow = t >> 1, scol = (t & 1) * 16;
  for (int k0 = 0; k0 < K; k0 += 32) {
    const uint16_t* ag = A + (size_t)(m0 + srow) * K + k0 + scol;
    const uint16_t* bg = BT + (size_t)(n0 + srow) * K + k0 + scol;
    uint4 av0 = *(const uint4*)ag;
    uint4 av1 = *(const uint4*)(ag + 8);
    uint4 bv0 = *(const uint4*)bg;
    uint4 bv1 = *(const uint4*)(bg + 8);
    __syncthreads();
    *(uint4*)(As + srow * 40 + scol) = av0;
    *(uint4*)(As + srow * 40 + scol + 8) = av1;
    *(uint4*)(Bs + srow * 40 + scol) = bv0;
    *(uint4*)(Bs + srow * 40 + scol + 8) = bv1;
    __syncthreads();
    bf16x8 af[4], bfr[4];
#pragma unroll
    for (int i = 0; i < 4; i++)
      af[i] = *(const bf16x8*)(As + (wm + i * 16 + l16) * 40 + quad * 8);
#pragma unroll
    for (int j = 0; j < 4; j++)
      bfr[j] = *(const bf16x8*)(Bs + (wn + j * 16 + l16) * 40 + quad * 8);
#pragma unroll
    for (int i = 0; i < 4; i++)
#pragma unroll
      for (int j = 0; j < 4; j++)
        acc[i][j] = __builtin_amdgcn_mfma_f32_16x16x32_bf16(af[i], bfr[j], acc[i][j], 0, 0, 0);
  }
#pragma unroll
  for (int i = 0; i < 4; i++)
#pragma unroll
    for (int j = 0; j < 4; j++) {
      int col = n0 + wn + j * 16 + l16;
      float bval = bias[col];
#pragma unroll
      for (int r = 0; r < 4; r++) {
        int row = m0 + wm + i * 16 + quad * 4 + r;
        x[(size_t)row * 1024 + col] = acc[i][j][r] + bval + resid[(size_t)row * 1024 + col];
      }
    }
}

// ---------------- fused attention v3 ----------------
// 8 waves (512 thr), QBLK=128 (wave w owns q-rows w*16..w*16+15), KVBLK=64.
// K/V tiles staged coalesced into double-buffered LDS shared by all 8 waves;
// register-staged prefetch (issue loads before the single per-step barrier,
// ds_write after). Swapped-operand QK^T (lane owns q-row l16), packed-bit mask,
// in-register rowsum (shfl_xor 16/32), one non-temporal attn write, wave-private
// Ps LDS relayout for the PV A-fragment.
#define KSZ (64 * 72)
__global__ __launch_bounds__(512) void fused_attn(
    const uint16_t* __restrict__ qh,              // [BH,S,64]
    const uint16_t* __restrict__ kh,              // [BH,S,64]
    const uint16_t* __restrict__ vT,              // [BH,64,S]
    const unsigned long long* __restrict__ pmask, // [B*S, S/64] bit set -> masked
    float* __restrict__ attn,                     // [BH,S,S] normalized out
    uint16_t* __restrict__ ctx) {                 // [B,S,H*64]
  __shared__ uint16_t Ks[2 * KSZ];
  __shared__ uint16_t Vs[2 * KSZ];
  __shared__ uint16_t Ps[8][16 * 72];

  int m0 = blockIdx.x * 128;
  int bh = blockIdx.y;
  int b = bh >> 4;
  int tid = threadIdx.x;
  int wave = tid >> 6, lane = tid & 63;
  int quad = lane >> 4, l16 = lane & 15;

  int srow = tid >> 3;          // 0..63 (tile row)
  int scol = (tid & 7) * 8;     // 0..56 (uint16 units, 16B chunks)

  int m = m0 + wave * 16 + l16;  // this lane's q-row
  const unsigned long long* pmr = pmask + (size_t)(b * Sc + m) * (Sc / 64);

  // loop-invariant Q fragments (B-operand)
  const uint16_t* qg = qh + (size_t)(bh * Sc + m) * Dc;
  bf16x8 qf0 = *(const bf16x8*)(qg + quad * 8);
  bf16x8 qf1 = *(const bf16x8*)(qg + 32 + quad * 8);

  const uint16_t* kbase = kh + (size_t)bh * Sc * Dc;
  const uint16_t* vbase = vT + (size_t)bh * Dc * Sc;
  const int NT = Sc / 64;  // 32

  // ---------------- pass 1: rowsums ----------------
  // prologue: stage tile 0 into buf 0
  *(uint4*)(Ks + srow * 72 + scol) = *(const uint4*)(kbase + (size_t)srow * Dc + scol);
  float rs = 0.0f;
  for (int t = 0; t < NT; t++) {
    uint4 kn;
    if (t + 1 < NT)
      kn = *(const uint4*)(kbase + (size_t)((t + 1) * 64 + srow) * Dc + scol);
    __syncthreads();
    const uint16_t* Kb = Ks + (t & 1) * KSZ;
    unsigned long long mk = pmr[t];
    f32x4 sacc[4];
#pragma unroll
    for (int j = 0; j < 4; j++) sacc[j] = (f32x4)(0.0f);
#pragma unroll
    for (int j = 0; j < 4; j++) {
      const uint16_t* kr = Kb + (j * 16 + l16) * 72;
      bf16x8 kf0 = *(const bf16x8*)(kr + quad * 8);
      bf16x8 kf1 = *(const bf16x8*)(kr + 32 + quad * 8);
      sacc[j] = __builtin_amdgcn_mfma_f32_16x16x32_bf16(kf0, qf0, sacc[j], 0, 0, 0);
      sacc[j] = __builtin_amdgcn_mfma_f32_16x16x32_bf16(kf1, qf1, sacc[j], 0, 0, 0);
    }
#pragma unroll
    for (int j = 0; j < 4; j++) {
      int base = j * 16 + quad * 4;
#pragma unroll
      for (int r = 0; r < 4; r++) {
        float e = __expf(sacc[j][r] * 0.125f);
        rs += ((mk >> (base + r)) & 1ull) ? 0.0f : e;
      }
    }
    if (t + 1 < NT)
      *(uint4*)(Ks + ((t + 1) & 1) * KSZ + srow * 72 + scol) = kn;
  }
  rs += __shfl_xor(rs, 16);
  rs += __shfl_xor(rs, 32);
  float rv = 1.0f / rs;

  // ---------------- pass 2: normalize + write attn + PV ----------------
  __syncthreads();  // protect buf0 overwrite vs pass-1 stragglers
  *(uint4*)(Ks + srow * 72 + scol) = *(const uint4*)(kbase + (size_t)srow * Dc + scol);
  *(uint4*)(Vs + srow * 72 + scol) = *(const uint4*)(vbase + (size_t)srow * Sc + scol);

  f32x4 cacc[4];
#pragma unroll
  for (int j = 0; j < 4; j++) cacc[j] = (f32x4)(0.0f);
  uint16_t* Pw = Ps[wave];

  for (int t = 0; t < NT; t++) {
    int k0 = t * 64;
    uint4 kn, vn;
    if (t + 1 < NT) {
      kn = *(const uint4*)(kbase + (size_t)(k0 + 64 + srow) * Dc + scol);
      vn = *(const uint4*)(vbase + (size_t)srow * Sc + k0 + 64 + scol);
    }
    __syncthreads();
    const uint16_t* Kb = Ks + (t & 1) * KSZ;
    const uint16_t* Vb = Vs + (t & 1) * KSZ;
    unsigned long long mk = pmr[t];
    f32x4 sacc[4];
#pragma unroll
    for (int j = 0; j < 4; j++) sacc[j] = (f32x4)(0.0f);
#pragma unroll
    for (int j = 0; j < 4; j++) {
      const uint16_t* kr = Kb + (j * 16 + l16) * 72;
      bf16x8 kf0 = *(const bf16x8*)(kr + quad * 8);
      bf16x8 kf1 = *(const bf16x8*)(kr + 32 + quad * 8);
      sacc[j] = __builtin_amdgcn_mfma_f32_16x16x32_bf16(kf0, qf0, sacc[j], 0, 0, 0);
      sacc[j] = __builtin_amdgcn_mfma_f32_16x16x32_bf16(kf1, qf1, sacc[j], 0, 0, 0);
    }
    float* arow = attn + (size_t)(bh * Sc + m) * Sc + k0;
#pragma unroll
    for (int j = 0; j < 4; j++) {
      int base = j * 16 + quad * 4;
      float p0 = ((mk >> (base + 0)) & 1ull) ? 0.0f : __expf(sacc[j][0] * 0.125f) * rv;
      float p1 = ((mk >> (base + 1)) & 1ull) ? 0.0f : __expf(sacc[j][1] * 0.125f) * rv;
      float p2 = ((mk >> (base + 2)) & 1ull) ? 0.0f : __expf(sacc[j][2] * 0.125f) * rv;
      float p3 = ((mk >> (base + 3)) & 1ull) ? 0.0f : __expf(sacc[j][3] * 0.125f) * rv;
      f32x4 wv; wv[0] = p0; wv[1] = p1; wv[2] = p2; wv[3] = p3;
      __builtin_nontemporal_store(wv, (f32x4*)(arow + base));  // write-once stream
      union { uint16_t u[4]; uint2 v; } pk;
      pk.u[0] = f2b(p0); pk.u[1] = f2b(p1); pk.u[2] = f2b(p2); pk.u[3] = f2b(p3);
      *(uint2*)(Pw + l16 * 72 + base) = pk.v;  // wave-private: no barrier needed
    }
    // PV: A = P fragment via wave-private LDS relayout, B = V^T from LDS tile
    bf16x8 pf0 = *(const bf16x8*)(Pw + l16 * 72 + quad * 8);
    bf16x8 pf1 = *(const bf16x8*)(Pw + l16 * 72 + 32 + quad * 8);
#pragma unroll
    for (int j = 0; j < 4; j++) {
      const uint16_t* vr = Vb + (j * 16 + l16) * 72;
      bf16x8 vf0 = *(const bf16x8*)(vr + quad * 8);
      bf16x8 vf1 = *(const bf16x8*)(vr + 32 + quad * 8);
      cacc[j] = __builtin_amdgcn_mfma_f32_16x16x32_bf16(pf0, vf0, cacc[j], 0, 0, 0);
      cacc[j] = __builtin_amdgcn_mfma_f32_16x16x32_bf16(pf1, vf1, cacc[j], 0, 0, 0);
    }
    if (t + 1 < NT) {
      *(uint4*)(Ks + ((t + 1) & 1) * KSZ + srow * 72 + scol) = kn;
      *(uint4*)(Vs + ((t + 1) & 1) * KSZ + srow * 72 + scol) = vn;
    }
  }
  // epilogue: ctx write (row = quad*4+r within wave's 16 rows, col = l16)
  int h = bh & 15;
#pragma unroll
  for (int j = 0; j < 4; j++) {
    int d = j * 16 + l16;
#pragma unroll
    for (int r = 0; r < 4; r++) {
      int s = m0 + wave * 16 + quad * 4 + r;
      ctx[(size_t)(b * Sc + s) * (Hc * Dc) + h * Dc + d] = f2b(cacc[j][r]);
    }
  }
}

// ---------------- LayerNorm ----------------
__global__ __launch_bounds__(256) void ln_kernel(
    const float* __restrict__ x, const float* __restrict__ gamma,
    const float* __restrict__ beta, float* __restrict__ y) {
  int row = blockIdx.x;
  int t = threadIdx.x;
  const float* xr = x + (size_t)row * 1024;
  float4 v = *(const float4*)(xr + t * 4);
  float s = v.x + v.y + v.z + v.w;
  float s2 = v.x * v.x + v.y * v.y + v.z * v.z + v.w * v.w;
#pragma unroll
  for (int o = 1; o < 64; o <<= 1) {
    s += __shfl_xor(s, o);
    s2 += __shfl_xor(s2, o);
  }
  __shared__ float ss[4], ss2[4];
  int wave = t >> 6, lane = t & 63;
  if (lane == 0) { ss[wave] = s; ss2[wave] = s2; }
  __syncthreads();
  s = ss[0] + ss[1] + ss[2] + ss[3];
  s2 = ss2[0] + ss2[1] + ss2[2] + ss2[3];
  float mu = s * (1.0f / 1024.0f);
  float var = s2 * (1.0f / 1024.0f) - mu * mu;
  float rstd = rsqrtf(var + 1e-5f);
  float4 g = *(const float4*)(gamma + t * 4);
  float4 be = *(const float4*)(beta + t * 4);
  float4 o;
  o.x = (v.x - mu) * rstd * g.x + be.x;
  o.y = (v.y - mu) * rstd * g.y + be.y;
  o.z = (v.z - mu) * rstd * g.z + be.z;
  o.w = (v.w - mu) * rstd * g.w + be.w;
  *(float4*)(y + (size_t)row * 1024 + t * 4) = o;
}

extern "C" void kernel_launch(void* const* d_in, const int* in_sizes, int n_in,
                              void* d_out, int out_size, void* d_ws, size_t ws_size,
                              hipStream_t stream) {
  const float* Q = (const float*)d_in[0];
  const float* K = (const float*)d_in[1];
  const float* V = (const float*)d_in[2];
  const int* mask = (const int*)d_in[3];
  const float* Wq = (const float*)d_in[4];
  const float* bq = (const float*)d_in[5];
  const float* Wk = (const float*)d_in[6];
  const float* bk = (const float*)d_in[7];
  const float* Wv = (const float*)d_in[8];
  const float* bv = (const float*)d_in[9];
  const float* Wo = (const float*)d_in[10];
  const float* bo = (const float*)d_in[11];
  const float* gamma = (const float*)d_in[12];
  const float* beta = (const float*)d_in[13];

  float* y = (float*)d_out;                           // [B,S,E]
  float* attn = (float*)d_out + (size_t)BSc * Ec;     // [B,H,S,S]

  char* ws = (char*)d_ws;
  size_t off = 0;
  auto alloc = [&](size_t bytes) -> void* {
    void* p = ws + off;
    off = (off + bytes + 255) & ~(size_t)255;
    return p;
  };
  uint16_t* Qb  = (uint16_t*)alloc((size_t)BSc * Ec * 2);
  uint16_t* Kb  = (uint16_t*)alloc((size_t)BSc * Ec * 2);
  uint16_t* Vb  = (uint16_t*)alloc((size_t)BSc * Ec * 2);
  uint16_t* WqT = (uint16_t*)alloc((size_t)Ec * Ec * 2);
  uint16_t* WkT = (uint16_t*)alloc((size_t)Ec * Ec * 2);
  uint16_t* WvT = (uint16_t*)alloc((size_t)Ec * Ec * 2);
  uint16_t* WoT = (uint16_t*)alloc((size_t)Ec * Ec * 2);
  uint16_t* qh  = (uint16_t*)alloc((size_t)BHc * Sc * Dc * 2);  // [BH,S,64]
  uint16_t* kh  = (uint16_t*)alloc((size_t)BHc * Sc * Dc * 2);  // [BH,S,64]
  uint16_t* vT  = (uint16_t*)alloc((size_t)BHc * Dc * Sc * 2);  // [BH,64,S]
  uint16_t* ctx = (uint16_t*)alloc((size_t)BSc * Ec * 2);       // [B,S,1024]
  float* xres   = (float*)alloc((size_t)BSc * Ec * 4);
  unsigned long long* pm = (unsigned long long*)alloc((size_t)Bc * Sc * (Sc / 64) * 8);

  const int n_qkv = BSc * Ec;  // 4,194,304
  const int n64 = Bc * Sc * (Sc / 64);  // 131072

  // 1) casts + mask pack
  conv_bf16<<<n_qkv / 1024, 256, 0, stream>>>(Q, Qb, n_qkv);
  conv_bf16<<<n_qkv / 1024, 256, 0, stream>>>(K, Kb, n_qkv);
  conv_bf16<<<n_qkv / 1024, 256, 0, stream>>>(V, Vb, n_qkv);
  pack_mask<<<n64 / 4, 256, 0, stream>>>(mask, pm, n64);
  // 2) weight transposes
  dim3 tg(32, 32);
  transpose_bf16<<<tg, 256, 0, stream>>>(Wq, WqT);
  transpose_bf16<<<tg, 256, 0, stream>>>(Wk, WkT);
  transpose_bf16<<<tg, 256, 0, stream>>>(Wv, WvT);
  transpose_bf16<<<tg, 256, 0, stream>>>(Wo, WoT);
  // 3) QKV projections
  dim3 pg(Ec / 128, BSc / 128);  // (8, 32)
  gemm_proj<<<pg, 256, 0, stream>>>(Qb, WqT, bq, qh, 0);
  gemm_proj<<<pg, 256, 0, stream>>>(Kb, WkT, bk, kh, 0);
  gemm_proj<<<pg, 256, 0, stream>>>(Vb, WvT, bv, vT, 1);
  // 4) fused attention (8-wave, LDS double-buffered, 1 barrier/step)
  dim3 fg(Sc / 128, BHc);  // (16, 32)
  fused_attn<<<fg, 512, 0, stream>>>(qh, kh, vT, pm, attn, ctx);
  // 5) out projection + residual
  gemm_out<<<pg, 256, 0, stream>>>(ctx, WoT, bo, Q, xres);
  // 6) LayerNorm
  ln_kernel<<<BSc, 256, 0, stream>>>(xres, gamma, beta, y);
}